// Round 6
// baseline (1531.395 us; speedup 1.0000x reference)
//
#include <hip/hip_runtime.h>
#include <cstdint>
#include <cstddef>

typedef unsigned short u16;
typedef __attribute__((ext_vector_type(8))) short short8;
typedef __attribute__((ext_vector_type(8))) u16 ushort8;
typedef __attribute__((ext_vector_type(4))) float float4_t;

#define BB 8
#define NN 8192
#define DD 64
#define NTILES 64            // 8192 / 128 column tiles
#define TILE_SHORTS 8192     // 128 points * 64 k (bf16)
#define LDS_STRIDE 68        // 64 floats + 4 pad (bank spread)

__device__ inline u16 f32_to_bf16(float f) {
  unsigned u = __float_as_uint(f);
  u += 0x7FFFu + ((u >> 16) & 1u);   // RNE
  return (u16)(u >> 16);
}

__device__ inline unsigned enc_ord(float f) {
  unsigned u = __float_as_uint(f);
  return (u & 0x80000000u) ? ~u : (u | 0x80000000u);
}
__device__ inline float dec_ord(unsigned u) {
  return __uint_as_float((u & 0x80000000u) ? (u & 0x7fffffffu) : ~u);
}

// ---------------------------------------------------------------------------
// K1: one block = one 128x64 tile. Coalesced read-once -> LDS -> swizzled
// bf16 tile (MFMA fragment chunk order) + 0.5*|row|^2. Also zeroes out[] and
// (fallback only) the ordered-uint col-max buffer.
// Chunk layout per tile: [I(8)][s(2)] chunks of 1KB; within a chunk lane
// l (l=qq*16+rl) holds point I*16+rl, k = s*32+qq*8+j (j=0..7, 16B).
// ---------------------------------------------------------------------------
__global__ __launch_bounds__(256) void pre_kernel(
    const float* __restrict__ x, const float* __restrict__ y,
    u16* __restrict__ xs, u16* __restrict__ ys,
    float* __restrict__ x2h, float* __restrict__ y2h,
    unsigned* __restrict__ colmax_u, float* __restrict__ out,
    const int use_part)
{
  __shared__ float stage[128 * LDS_STRIDE];   // 34 KB

  const int bid = blockIdx.x;          // 1024: 0..511 -> x, 512..1023 -> y
  const int tid = threadIdx.x;

  if (!use_part && bid < 256) colmax_u[(bid << 8) | tid] = 0u;
  if (bid == 0 && tid == 0) out[0] = 0.f;

  const bool isY = bid >= 512;
  const int t = bid & 511;             // tile id = b*64 + nt
  const float* src = (isY ? y : x) + (size_t)t * (128 * DD);
  u16* dst = (isY ? ys : xs) + (size_t)t * TILE_SHORTS;
  float* s2 = (isY ? y2h : x2h) + t * 128;

  // ---- coalesced load: 8 rounds of float4 per thread ----
#pragma unroll
  for (int c = 0; c < 8; ++c) {
    const int idx = c * 256 + tid;     // float4 index within tile (0..2047)
    float4 f = ((const float4*)src)[idx];
    const int r = idx >> 4, kc = idx & 15;
    *(float4*)&stage[r * LDS_STRIDE + kc * 4] = f;
  }
  __syncthreads();

  // ---- 0.5*|row|^2: 2 threads per row ----
  {
    const int r = tid >> 1, half = tid & 1;
    const float* rp = &stage[r * LDS_STRIDE + half * 32];
    float ss = 0.f;
#pragma unroll
    for (int k = 0; k < 8; ++k) {
      float4 f = *(const float4*)&rp[k * 4];
      ss += f.x*f.x + f.y*f.y + f.z*f.z + f.w*f.w;
    }
    ss += __shfl_xor(ss, 1);
    if (half == 0) s2[r] = 0.5f * ss;
  }

  // ---- swizzle out: 4 ushort8 units per thread, 1KB/wave stores ----
  {
    const int w = tid >> 6, lane = tid & 63;
    const int qq = lane >> 4, rl = lane & 15;
#pragma unroll
    for (int u = 0; u < 4; ++u) {
      const int chunk = w * 4 + u;
      const int I = chunk >> 1, s = chunk & 1;
      const float* rp = &stage[(I*16 + rl) * LDS_STRIDE + s*32 + qq*8];
      ushort8 o;
#pragma unroll
      for (int j = 0; j < 8; ++j) o[j] = f32_to_bf16(rp[j]);
      *(ushort8*)(dst + chunk*512 + lane*8) = o;
    }
  }
}

// ---------------------------------------------------------------------------
// K2: main. Barrier-free, software-pipelined K-loop: acc double-buffer at
// stage granularity — the epilogue of stage k (pure max trees, no pending
// dependencies) overlaps the MFMA issue/drain of stage k+1. C-init carries
// the exact fp32 -(x^2+y^2)/2, so acc = -d^2/2 and BOTH epilogues are pure
// max. Plain disjoint colpart stores (no in-loop atomics -> vmcnt queue
// never clogs). Block = 4 waves; wave owns 128 rows x 32 cols; 2 blocks/CU.
// Grid 512 = 8 b (XCD-affine) x 64 nt.
// ---------------------------------------------------------------------------
__global__ __launch_bounds__(256, 2) void main_kernel(
    const u16* __restrict__ xs, const u16* __restrict__ ys,
    const float* __restrict__ x2h, const float* __restrict__ y2h,
    float* __restrict__ a_min, float* __restrict__ colpart,
    unsigned* __restrict__ colmax_u, const int use_part)
{
  __shared__ float rowbuf[4][128];

  const int bid = blockIdx.x;            // 512
  const int b   = bid & 7;               // XCD-affine
  const int nt  = bid >> 3;
  const int tid = threadIdx.x;
  const int w = tid >> 6, lane = tid & 63;   // w = column-slice owner
  const int l15 = lane & 15, q = lane >> 4;
  const int n0 = nt << 7;

  // ---- A fragments: all 128 rows, both K-halves, pinned in registers ----
  const u16* xs_tile = xs + (size_t)((b << 6) | nt) * TILE_SHORTS;
  short8 afr[8][2];
#pragma unroll
  for (int i = 0; i < 8; ++i)
#pragma unroll
    for (int s = 0; s < 2; ++s)
      afr[i][s] = *(const short8*)(xs_tile + (i*2 + s)*512 + lane*8);

  // ---- -x2/2 per row (fp32 exact, goes into C-init) ----
  float4_t negx2[8];
  const float* x2b = x2h + b*NN + n0;
#pragma unroll
  for (int i = 0; i < 8; ++i) {
    float4_t v = *(const float4_t*)(x2b + i*16 + q*4);
    negx2[i] = {-v[0], -v[1], -v[2], -v[3]};
  }

  float rowmax[8][4];
#pragma unroll
  for (int i = 0; i < 8; ++i)
#pragma unroll
    for (int r = 0; r < 4; ++r) rowmax[i][r] = -3.0e38f;

  const float* y2b = y2h + b*NN;
  const u16* ys_b  = ys + (size_t)(b << 6) * TILE_SHORTS;
  float* colp      = colpart + (size_t)((b << 6) | nt) * NN;
  unsigned* colu   = colmax_u + b*NN;

  // MFMA stage: acc = x.y - x2/2 - y2/2 = -d^2/2 (C-init exact fp32)
#define MFMA_STAGE(ACC, B0, B1, Y2S)                                           \
  do {                                                                         \
    const float y2s_ = (Y2S);                                                  \
    _Pragma("unroll") for (int i = 0; i < 8; ++i) {                            \
      float4_t ci = {negx2[i][0] - y2s_, negx2[i][1] - y2s_,                   \
                     negx2[i][2] - y2s_, negx2[i][3] - y2s_};                  \
      ACC[i] = __builtin_amdgcn_mfma_f32_16x16x32_bf16(afr[i][0], B0, ci, 0, 0, 0); \
    }                                                                          \
    _Pragma("unroll") for (int i = 0; i < 8; ++i)                              \
      ACC[i] = __builtin_amdgcn_mfma_f32_16x16x32_bf16(afr[i][1], B1, ACC[i], 0, 0, 0); \
  } while (0)

  // epilogue: pure max trees on acc = -d^2/2 (no pending deps)
#define EPI(ACC, MBASE)                                                        \
  do {                                                                         \
    float cm = fmaxf(fmaxf(ACC[0][0], ACC[0][1]), fmaxf(ACC[0][2], ACC[0][3]));\
    _Pragma("unroll") for (int i = 1; i < 8; ++i) {                            \
      float mi = fmaxf(fmaxf(ACC[i][0], ACC[i][1]), fmaxf(ACC[i][2], ACC[i][3]));\
      cm = fmaxf(cm, mi);                                                      \
    }                                                                          \
    cm = fmaxf(cm, __shfl_xor(cm, 16));                                        \
    cm = fmaxf(cm, __shfl_xor(cm, 32));                                        \
    if (q == 0) {                                                              \
      if (use_part) colp[(MBASE) + l15] = cm;                                  \
      else          atomicMax(&colu[(MBASE) + l15], enc_ord(cm));              \
    }                                                                          \
    _Pragma("unroll") for (int i = 0; i < 8; ++i)                              \
      _Pragma("unroll") for (int r = 0; r < 4; ++r)                            \
        rowmax[i][r] = fmaxf(rowmax[i][r], ACC[i][r]);                         \
  } while (0)

  // ---- prologue: tile 0 fragments + first MFMA stage (j=0) ----
  short8 bcur0[2], bcur1[2], bnx0[2], bnx1[2];
  float y2c0, y2c1;
  {
    const u16* g = ys_b;
    bcur0[0] = *(const short8*)(g + ((2*w + 0)*2 + 0)*512 + lane*8);
    bcur0[1] = *(const short8*)(g + ((2*w + 0)*2 + 1)*512 + lane*8);
    bcur1[0] = *(const short8*)(g + ((2*w + 1)*2 + 0)*512 + lane*8);
    bcur1[1] = *(const short8*)(g + ((2*w + 1)*2 + 1)*512 + lane*8);
    y2c0 = y2b[w*32 + l15];
    y2c1 = y2b[w*32 + 16 + l15];
  }
  float4_t accA[8], accB[8];
  MFMA_STAGE(accA, bcur0[0], bcur0[1], y2c0);

#pragma unroll 2
  for (int mt = 0; mt < NTILES - 1; ++mt) {
    // prefetch tile mt+1
    const u16* g = ys_b + (size_t)(mt + 1) * TILE_SHORTS;
    bnx0[0] = *(const short8*)(g + ((2*w + 0)*2 + 0)*512 + lane*8);
    bnx0[1] = *(const short8*)(g + ((2*w + 0)*2 + 1)*512 + lane*8);
    bnx1[0] = *(const short8*)(g + ((2*w + 1)*2 + 0)*512 + lane*8);
    bnx1[1] = *(const short8*)(g + ((2*w + 1)*2 + 1)*512 + lane*8);
    float y2n0 = y2b[(mt + 1)*128 + w*32 + l15];
    float y2n1 = y2b[(mt + 1)*128 + w*32 + 16 + l15];

    // stage (mt, j1) into accB, then epilogue of accA (results long ready)
    MFMA_STAGE(accB, bcur1[0], bcur1[1], y2c1);
    EPI(accA, (mt << 7) + w*32);

    // rotate to tile mt+1 (unroll-2 lets renaming elide the copies)
    bcur0[0] = bnx0[0]; bcur0[1] = bnx0[1];
    bcur1[0] = bnx1[0]; bcur1[1] = bnx1[1];
    y2c0 = y2n0; y2c1 = y2n1;

    // stage (mt+1, j0) into accA, then epilogue of accB
    MFMA_STAGE(accA, bcur0[0], bcur0[1], y2c0);
    EPI(accB, (mt << 7) + w*32 + 16);
  }
  // tail: tile 63 j1 + both epilogues
  MFMA_STAGE(accB, bcur1[0], bcur1[1], y2c1);
  EPI(accA, ((NTILES - 1) << 7) + w*32);
  EPI(accB, ((NTILES - 1) << 7) + w*32 + 16);

#undef MFMA_STAGE
#undef EPI

  // ---- row side finalize: shfl over cols (l15), then 4-wave LDS combine ----
#pragma unroll
  for (int i = 0; i < 8; ++i)
#pragma unroll
    for (int r = 0; r < 4; ++r) {
      float v = rowmax[i][r];
      v = fmaxf(v, __shfl_xor(v, 1));
      v = fmaxf(v, __shfl_xor(v, 2));
      v = fmaxf(v, __shfl_xor(v, 4));
      v = fmaxf(v, __shfl_xor(v, 8));
      rowmax[i][r] = v;
    }
  if (l15 == 0) {
#pragma unroll
    for (int i = 0; i < 8; ++i)
#pragma unroll
      for (int r = 0; r < 4; ++r)
        rowbuf[w][i*16 + q*4 + r] = rowmax[i][r];
  }
  __syncthreads();
  if (tid < 128) {
    float v = fmaxf(fmaxf(rowbuf[0][tid], rowbuf[1][tid]),
                    fmaxf(rowbuf[2][tid], rowbuf[3][tid]));   // -min(d^2)/2
    a_min[b*NN + n0 + tid] = sqrtf(fmaxf(-2.f * v, 0.f));
  }
}

// ---------------------------------------------------------------------------
// K3: col combine over 64 nt + sqrt, add a_min; block sum; atomicAdd out.
// ---------------------------------------------------------------------------
__global__ __launch_bounds__(256) void reduce_kernel(
    const float* __restrict__ colpart, const unsigned* __restrict__ colmax_u,
    const float* __restrict__ a_min, float* __restrict__ out,
    const int use_part)
{
  const int bid = blockIdx.x;          // 256
  const int tid = threadIdx.x;
  const int g = bid*256 + tid;         // 0..65535
  const int b = g >> 13, m = g & (NN - 1);

  float vc;
  if (use_part) {
    vc = -3.0e38f;
#pragma unroll 8
    for (int nt = 0; nt < 64; ++nt)
      vc = fmaxf(vc, colpart[(size_t)((b << 6) | nt) * NN + m]);
  } else {
    vc = dec_ord(colmax_u[g]);
  }
  float s = sqrtf(fmaxf(-2.f * vc, 0.f))   // nearest-x for this y
          + a_min[g];                      // nearest-y for this x

#pragma unroll
  for (int d = 1; d < 64; d <<= 1) s += __shfl_xor(s, d);
  __shared__ float wsum[4];
  if ((tid & 63) == 0) wsum[tid >> 6] = s;
  __syncthreads();
  if (tid == 0)
    atomicAdd(out, (wsum[0] + wsum[1] + wsum[2] + wsum[3]) * (1.0f / 65536.0f));
}

// ---------------------------------------------------------------------------
extern "C" void kernel_launch(void* const* d_in, const int* in_sizes, int n_in,
                              void* d_out, int out_size, void* d_ws, size_t ws_size,
                              hipStream_t stream) {
  const float* x = (const float*)d_in[0];
  const float* y = (const float*)d_in[1];
  float* out = (float*)d_out;

  char* p = (char*)d_ws;
  u16* xs = (u16*)p;            p += (size_t)512 * 16384;   // 8 MiB
  u16* ys = (u16*)p;            p += (size_t)512 * 16384;   // 8 MiB
  float* x2h = (float*)p;       p += (size_t)65536 * 4;
  float* y2h = (float*)p;       p += (size_t)65536 * 4;
  float* a_min = (float*)p;     p += (size_t)65536 * 4;
  char* tail = p;
  // partial path: colpart 16 MiB; fallback: 256 KiB ordered-uint atomics
  float* colpart = (float*)tail;
  unsigned* colmax_u = (unsigned*)tail;
  const size_t need_part = (size_t)(tail - (char*)d_ws) + (size_t)512 * 8192 * 4;
  const int use_part = (ws_size >= need_part) ? 1 : 0;

  pre_kernel<<<dim3(1024), dim3(256), 0, stream>>>(x, y, xs, ys, x2h, y2h,
                                                   colmax_u, out, use_part);
  main_kernel<<<dim3(512), dim3(256), 0, stream>>>(xs, ys, x2h, y2h, a_min,
                                                   colpart, colmax_u, use_part);
  reduce_kernel<<<dim3(256), dim3(256), 0, stream>>>(colpart, colmax_u, a_min,
                                                     out, use_part);
}

// Round 7
// 167.004 us; speedup vs baseline: 9.1698x; 9.1698x over previous
//
#include <hip/hip_runtime.h>
#include <cstdint>
#include <cstddef>

typedef unsigned short u16;
typedef __attribute__((ext_vector_type(8))) short short8;
typedef __attribute__((ext_vector_type(8))) u16 ushort8;
typedef __attribute__((ext_vector_type(4))) float float4_t;

#define BB 8
#define NN 8192
#define DD 64
#define NTILES 64            // 8192 / 128 column tiles
#define TILE_SHORTS 8192     // 128 points * 64 k (bf16)
#define LDS_STRIDE 68        // 64 floats + 4 pad (bank spread)

__device__ inline u16 f32_to_bf16(float f) {
  unsigned u = __float_as_uint(f);
  u += 0x7FFFu + ((u >> 16) & 1u);   // RNE
  return (u16)(u >> 16);
}

__device__ inline unsigned enc_ord(float f) {
  unsigned u = __float_as_uint(f);
  return (u & 0x80000000u) ? ~u : (u | 0x80000000u);
}
__device__ inline float dec_ord(unsigned u) {
  return __uint_as_float((u & 0x80000000u) ? (u & 0x7fffffffu) : ~u);
}

// ---------------------------------------------------------------------------
// K1: one block = one 128x64 tile. Coalesced read-once -> LDS -> swizzled
// bf16 tile (MFMA fragment chunk order) + 0.5*|row|^2. Also zeroes out[] and
// (fallback only) the ordered-uint col-max buffer.  [verified correct in R6]
// Chunk layout per tile: [I(8)][s(2)] chunks of 1KB; within a chunk lane
// l (l=qq*16+rl) holds point I*16+rl, k = s*32+qq*8+j (j=0..7, 16B).
// ---------------------------------------------------------------------------
__global__ __launch_bounds__(256) void pre_kernel(
    const float* __restrict__ x, const float* __restrict__ y,
    u16* __restrict__ xs, u16* __restrict__ ys,
    float* __restrict__ x2h, float* __restrict__ y2h,
    unsigned* __restrict__ colmax_u, float* __restrict__ out,
    const int use_part)
{
  __shared__ float stage[128 * LDS_STRIDE];   // 34 KB

  const int bid = blockIdx.x;          // 1024: 0..511 -> x, 512..1023 -> y
  const int tid = threadIdx.x;

  if (!use_part && bid < 256) colmax_u[(bid << 8) | tid] = 0u;
  if (bid == 0 && tid == 0) out[0] = 0.f;

  const bool isY = bid >= 512;
  const int t = bid & 511;             // tile id = b*64 + nt
  const float* src = (isY ? y : x) + (size_t)t * (128 * DD);
  u16* dst = (isY ? ys : xs) + (size_t)t * TILE_SHORTS;
  float* s2 = (isY ? y2h : x2h) + t * 128;

  // ---- coalesced load: 8 rounds of float4 per thread ----
#pragma unroll
  for (int c = 0; c < 8; ++c) {
    const int idx = c * 256 + tid;     // float4 index within tile (0..2047)
    float4 f = ((const float4*)src)[idx];
    const int r = idx >> 4, kc = idx & 15;
    *(float4*)&stage[r * LDS_STRIDE + kc * 4] = f;
  }
  __syncthreads();

  // ---- 0.5*|row|^2: 2 threads per row ----
  {
    const int r = tid >> 1, half = tid & 1;
    const float* rp = &stage[r * LDS_STRIDE + half * 32];
    float ss = 0.f;
#pragma unroll
    for (int k = 0; k < 8; ++k) {
      float4 f = *(const float4*)&rp[k * 4];
      ss += f.x*f.x + f.y*f.y + f.z*f.z + f.w*f.w;
    }
    ss += __shfl_xor(ss, 1);
    if (half == 0) s2[r] = 0.5f * ss;
  }

  // ---- swizzle out: 4 ushort8 units per thread, 1KB/wave stores ----
  {
    const int w = tid >> 6, lane = tid & 63;
    const int qq = lane >> 4, rl = lane & 15;
#pragma unroll
    for (int u = 0; u < 4; ++u) {
      const int chunk = w * 4 + u;
      const int I = chunk >> 1, s = chunk & 1;
      const float* rp = &stage[(I*16 + rl) * LDS_STRIDE + s*32 + qq*8];
      ushort8 o;
#pragma unroll
      for (int j = 0; j < 8; ++j) o[j] = f32_to_bf16(rp[j]);
      *(ushort8*)(dst + chunk*512 + lane*8) = o;
    }
  }
}

// ---------------------------------------------------------------------------
// K2: main — EXACT R3 structure (proven 88 us, no spill): barrier-free
// K-loop, j-sequential single acc bank, 1-iter register prefetch, plain
// disjoint colpart stores. Block = 4 waves; wave owns 128 rows x 32 cols;
// 2 blocks/CU. acc = xy - x2/2 via fp32 C-init. Grid 512 = 8 b x 64 nt.
// DO NOT add acc double-buffering or #pragma unroll here: live state is
// within ~30 regs of the 256 budget; R4/R6 additions spilled (10x cost).
// ---------------------------------------------------------------------------
__global__ __launch_bounds__(256, 2) void main_kernel(
    const u16* __restrict__ xs, const u16* __restrict__ ys,
    const float* __restrict__ x2h, const float* __restrict__ y2h,
    float* __restrict__ a_min, float* __restrict__ colpart,
    unsigned* __restrict__ colmax_u, const int use_part)
{
  __shared__ float rowbuf[4][128];

  const int bid = blockIdx.x;            // 512
  const int b   = bid & 7;               // XCD-affine
  const int nt  = bid >> 3;
  const int tid = threadIdx.x;
  const int w = tid >> 6, lane = tid & 63;   // w = column-slice owner
  const int l15 = lane & 15, q = lane >> 4;
  const int n0 = nt << 7;

  // ---- A fragments: all 128 rows, both K-halves, pinned in registers ----
  const u16* xs_tile = xs + (size_t)((b << 6) | nt) * TILE_SHORTS;
  short8 afr[8][2];
#pragma unroll
  for (int i = 0; i < 8; ++i)
#pragma unroll
    for (int s = 0; s < 2; ++s)
      afr[i][s] = *(const short8*)(xs_tile + (i*2 + s)*512 + lane*8);

  // ---- C-init quads: -x2/2 per row (fp32 exact) ----
  float4_t negx2[8];
  const float* x2b = x2h + b*NN + n0;
#pragma unroll
  for (int i = 0; i < 8; ++i) {
    float4_t v = *(const float4_t*)(x2b + i*16 + q*4);
    negx2[i] = {-v[0], -v[1], -v[2], -v[3]};
  }

  float rowmax[8][4];
#pragma unroll
  for (int i = 0; i < 8; ++i)
#pragma unroll
    for (int r = 0; r < 4; ++r) rowmax[i][r] = -3.0e38f;

  const float* y2b = y2h + b*NN;
  const u16* ys_b  = ys + (size_t)(b << 6) * TILE_SHORTS;
  float* colp      = colpart + (size_t)((b << 6) | nt) * NN;
  unsigned* colu   = colmax_u + b*NN;

  // ---- register prefetch for mt = 0 ----
  short8 bcur[2][2];
  float y2cur[2];
#pragma unroll
  for (int j = 0; j < 2; ++j) {
#pragma unroll
    for (int s = 0; s < 2; ++s)
      bcur[j][s] = *(const short8*)(ys_b + ((2*w + j)*2 + s)*512 + lane*8);
    y2cur[j] = y2b[w*32 + j*16 + l15];
  }

  for (int mt = 0; mt < NTILES; ++mt) {
    // prefetch mt+1 (clamped; uniform predicate-free codegen)
    const int mtn = (mt + 1 < NTILES) ? (mt + 1) : 0;
    short8 bnext[2][2];
    float y2next[2];
    const u16* g = ys_b + (size_t)mtn * TILE_SHORTS;
#pragma unroll
    for (int j = 0; j < 2; ++j) {
#pragma unroll
      for (int s = 0; s < 2; ++s)
        bnext[j][s] = *(const short8*)(g + ((2*w + j)*2 + s)*512 + lane*8);
      y2next[j] = y2b[mtn*128 + w*32 + j*16 + l15];
    }

    float cmax[2];
#pragma unroll
    for (int j = 0; j < 2; ++j) {
      // acc = xy - x2/2 (C carries exact fp32 -x2/2); j-sequential keeps
      // live accumulators at 8 x float4
      float4_t acc[8];
#pragma unroll
      for (int i = 0; i < 8; ++i)
        acc[i] = __builtin_amdgcn_mfma_f32_16x16x32_bf16(afr[i][0], bcur[j][0], negx2[i], 0, 0, 0);
#pragma unroll
      for (int i = 0; i < 8; ++i)
        acc[i] = __builtin_amdgcn_mfma_f32_16x16x32_bf16(afr[i][1], bcur[j][1], acc[i], 0, 0, 0);

      // col side: pure max over rows in-lane
      float m01 = fmaxf(fmaxf(acc[0][0], acc[0][1]), fmaxf(acc[0][2], acc[0][3]));
#pragma unroll
      for (int i = 1; i < 8; ++i) {
        float mi = fmaxf(fmaxf(acc[i][0], acc[i][1]), fmaxf(acc[i][2], acc[i][3]));
        m01 = fmaxf(m01, mi);
      }
      cmax[j] = m01;

      // row side: rowmax = max(acc - y2/2) = -min(d^2)/2
      const float y2j = y2cur[j];
#pragma unroll
      for (int i = 0; i < 8; ++i)
#pragma unroll
        for (int r = 0; r < 4; ++r)
          rowmax[i][r] = fmaxf(rowmax[i][r], acc[i][r] - y2j);
    }

    // col-max: combine q-groups (rows) via shuffles; wave-private, no barrier
#pragma unroll
    for (int j = 0; j < 2; ++j) {
      cmax[j] = fmaxf(cmax[j], __shfl_xor(cmax[j], 16));
      cmax[j] = fmaxf(cmax[j], __shfl_xor(cmax[j], 32));
    }
    float cv = (q & 1) ? cmax[1] : cmax[0];
    const int m = (mt << 7) + w*32 + q*16 + l15;   // valid for q<2
    if (q < 2) {
      if (use_part) colp[m] = cv;
      else          atomicMax(&colu[m], enc_ord(cv));
    }

#pragma unroll
    for (int j = 0; j < 2; ++j) {
#pragma unroll
      for (int s = 0; s < 2; ++s) bcur[j][s] = bnext[j][s];
      y2cur[j] = y2next[j];
    }
  }

  // ---- row side finalize: shfl over cols (l15), then 4-wave LDS combine ----
#pragma unroll
  for (int i = 0; i < 8; ++i)
#pragma unroll
    for (int r = 0; r < 4; ++r) {
      float v = rowmax[i][r];
      v = fmaxf(v, __shfl_xor(v, 1));
      v = fmaxf(v, __shfl_xor(v, 2));
      v = fmaxf(v, __shfl_xor(v, 4));
      v = fmaxf(v, __shfl_xor(v, 8));
      rowmax[i][r] = v;
    }
  if (l15 == 0) {
#pragma unroll
    for (int i = 0; i < 8; ++i)
#pragma unroll
      for (int r = 0; r < 4; ++r)
        rowbuf[w][i*16 + q*4 + r] = rowmax[i][r];
  }
  __syncthreads();
  if (tid < 128) {
    float v = fmaxf(fmaxf(rowbuf[0][tid], rowbuf[1][tid]),
                    fmaxf(rowbuf[2][tid], rowbuf[3][tid]));   // -min(d^2)/2
    a_min[b*NN + n0 + tid] = sqrtf(fmaxf(-2.f * v, 0.f));
  }
}

// ---------------------------------------------------------------------------
// K3: col combine over 64 nt + sqrt, add a_min; block sum; atomicAdd out.
// ---------------------------------------------------------------------------
__global__ __launch_bounds__(256) void reduce_kernel(
    const float* __restrict__ colpart, const unsigned* __restrict__ colmax_u,
    const float* __restrict__ y2h, const float* __restrict__ a_min,
    float* __restrict__ out, const int use_part)
{
  const int bid = blockIdx.x;          // 256
  const int tid = threadIdx.x;
  const int g = bid*256 + tid;         // 0..65535
  const int b = g >> 13, m = g & (NN - 1);

  float vc;
  if (use_part) {
    vc = -3.0e38f;
#pragma unroll 8
    for (int nt = 0; nt < 64; ++nt)
      vc = fmaxf(vc, colpart[(size_t)((b << 6) | nt) * NN + m]);
  } else {
    vc = dec_ord(colmax_u[g]);
  }
  float s = sqrtf(fmaxf(2.f*(y2h[g] - vc), 0.f))   // nearest-x for this y
          + a_min[g];                              // nearest-y for this x

#pragma unroll
  for (int d = 1; d < 64; d <<= 1) s += __shfl_xor(s, d);
  __shared__ float wsum[4];
  if ((tid & 63) == 0) wsum[tid >> 6] = s;
  __syncthreads();
  if (tid == 0)
    atomicAdd(out, (wsum[0] + wsum[1] + wsum[2] + wsum[3]) * (1.0f / 65536.0f));
}

// ---------------------------------------------------------------------------
extern "C" void kernel_launch(void* const* d_in, const int* in_sizes, int n_in,
                              void* d_out, int out_size, void* d_ws, size_t ws_size,
                              hipStream_t stream) {
  const float* x = (const float*)d_in[0];
  const float* y = (const float*)d_in[1];
  float* out = (float*)d_out;

  char* p = (char*)d_ws;
  u16* xs = (u16*)p;            p += (size_t)512 * 16384;   // 8 MiB
  u16* ys = (u16*)p;            p += (size_t)512 * 16384;   // 8 MiB
  float* x2h = (float*)p;       p += (size_t)65536 * 4;
  float* y2h = (float*)p;       p += (size_t)65536 * 4;
  float* a_min = (float*)p;     p += (size_t)65536 * 4;
  char* tail = p;
  // partial path: colpart 16 MiB; fallback: 256 KiB ordered-uint atomics
  float* colpart = (float*)tail;
  unsigned* colmax_u = (unsigned*)tail;
  const size_t need_part = (size_t)(tail - (char*)d_ws) + (size_t)512 * 8192 * 4;
  const int use_part = (ws_size >= need_part) ? 1 : 0;

  pre_kernel<<<dim3(1024), dim3(256), 0, stream>>>(x, y, xs, ys, x2h, y2h,
                                                   colmax_u, out, use_part);
  main_kernel<<<dim3(512), dim3(256), 0, stream>>>(xs, ys, x2h, y2h, a_min,
                                                   colpart, colmax_u, use_part);
  reduce_kernel<<<dim3(256), dim3(256), 0, stream>>>(colpart, colmax_u, y2h,
                                                     a_min, out, use_part);
}